// Round 6
// baseline (270.639 us; speedup 1.0000x reference)
//
#include <hip/hip_runtime.h>

#define SS 2048
#define DD 1024
#define HH 16
#define MM 4096
#define KK 1024

typedef __attribute__((ext_vector_type(8))) short bf16x8;
typedef __attribute__((ext_vector_type(4))) float f32x4;
typedef __attribute__((ext_vector_type(16))) float f32x16;
typedef __attribute__((ext_vector_type(4))) float float4_t;
typedef __attribute__((ext_vector_type(4))) short short4_t;

__device__ __forceinline__ short f2bf(float f) {
    union { float f; unsigned u; } x; x.f = f;
    unsigned r = x.u + 0x7fffu + ((x.u >> 16) & 1u);
    return (short)(r >> 16);
}
__device__ __forceinline__ float bf2f(short s) {
    union { unsigned u; float f; } x; x.u = ((unsigned)(unsigned short)s) << 16;
    return x.f;
}

__device__ __forceinline__ f32x4 mfma16(bf16x8 a, bf16x8 b, f32x4 c) {
    return __builtin_amdgcn_mfma_f32_16x16x32_bf16(a, b, c, 0, 0, 0);
}
__device__ __forceinline__ f32x16 mfma32(bf16x8 a, bf16x8 b, f32x16 c) {
    return __builtin_amdgcn_mfma_f32_32x32x16_bf16(a, b, c, 0, 0, 0);
}

__device__ __forceinline__ void gl_lds16(const void* g, void* l) {
    __builtin_amdgcn_global_load_lds(
        (const __attribute__((address_space(1))) void*)g,
        (__attribute__((address_space(3))) void*)l, 16, 0, 0);
}

__device__ __forceinline__ float exp2a(float x) {
    float r; asm("v_exp_f32 %0, %1" : "=v"(r) : "v"(x)); return r;
}
__device__ __forceinline__ int cvtpk(float lo, float hi) {
    int r; asm("v_cvt_pk_bf16_f32 %0, %1, %2" : "=v"(r) : "v"(lo), "v"(hi)); return r;
}
__device__ __forceinline__ void pswap(int& a, int& b) {
    asm("v_permlane32_swap_b32 %0, %1" : "+v"(a), "+v"(b));
}

// ---------------- fused conversion pass: fp32 -> bf16 (X planes + W planes) ----------------
__global__ __launch_bounds__(256)
void conv_all(const float* __restrict__ x0, const float* __restrict__ x1,
              const float* __restrict__ x2,
              const float* __restrict__ w0, const float* __restrict__ w1,
              const float* __restrict__ w2, const float* __restrict__ w3,
              short* __restrict__ Xb, short* __restrict__ Wb) {
    const int bid = blockIdx.x;
    const float* src;
    short* dst;
    size_t i;
    if (bid < 6144) {
        const int plane = bid >> 11, idx = bid & 2047;
        src = (plane == 0) ? x0 : (plane == 1) ? x1 : x2;
        i = ((size_t)idx * 256 + threadIdx.x) * 8;
        dst = Xb + (size_t)plane * MM * KK;
    } else {
        const int b2 = bid - 6144;
        const int plane = b2 >> 9, idx = b2 & 511;
        src = (plane == 0) ? w0 : (plane == 1) ? w1 : (plane == 2) ? w2 : w3;
        i = ((size_t)idx * 256 + threadIdx.x) * 8;
        dst = Wb + (size_t)plane * KK * KK;
    }
    float4_t a = *(const float4_t*)(src + i);
    float4_t b = *(const float4_t*)(src + i + 4);
    bf16x8 o;
#pragma unroll
    for (int e = 0; e < 4; ++e) { o[e] = f2bf(a[e]); o[4 + e] = f2bf(b[e]); }
    *(bf16x8*)(dst + i) = o;
}

// ---------------- bf16 GEMM core, BK=64, fragment-order LDS (conflict-free) ----------------
// A [M][K] bf16, W [N][K] bf16, C = A*W^T. Tile: 128 x (NI*32). 4 waves (2x2).
// LDS chunk layout (16B chunks): A chunk = wr*512 + mi*128 + ks*64 + lane
//                                B chunk = wc*(NI*128) + ni*128 + ks*64 + lane
// Staged linearly by chunk id; global source address carries the permutation.
template <int NI>
__device__ __forceinline__ void gemm_core(const short* __restrict__ A,
                                          const short* __restrict__ Bw,
                                          int m0, int n0,
                                          char* As, char* Bs,
                                          f32x4 acc[4][NI]) {
    const int tid = threadIdx.x;
    const int lane = tid & 63, w = tid >> 6;
    const int wr = w >> 1, wc = w & 1;

    // per-thread permuted global sources
    const short* srcA[4];
#pragma unroll
    for (int jj = 0; jj < 4; ++jj) {
        const int c = tid + jj * 256;
        const int arow = ((c >> 9) << 6) + (((c >> 7) & 3) << 4) + (c & 15);
        const int akc  = (((c >> 6) & 1) << 2) + ((c >> 4) & 3);
        srcA[jj] = A + (size_t)(m0 + arow) * KK + akc * 8;
    }
    const short* srcB[NI];
#pragma unroll
    for (int jj = 0; jj < NI; ++jj) {
        const int c = tid + jj * 256;
        const int wcb = c / (NI * 128), rem = c % (NI * 128);
        const int brow = wcb * (16 * NI) + ((rem >> 7) << 4) + (c & 15);
        const int bkc  = (((c >> 6) & 1) << 2) + ((c >> 4) & 3);
        srcB[jj] = Bw + (size_t)(n0 + brow) * KK + bkc * 8;
    }
    char* ldA = As + tid * 16;
    char* ldB = Bs + tid * 16;
    constexpr int ABYTES = 16384;
    constexpr int BBYTES = NI * 4096;

#define GSTAGE(buf, kofs)                                                   \
    { _Pragma("unroll")                                                     \
      for (int jj = 0; jj < 4; ++jj)                                        \
          gl_lds16(srcA[jj] + (kofs), ldA + (buf) * ABYTES + jj * 4096);    \
      _Pragma("unroll")                                                     \
      for (int jj = 0; jj < NI; ++jj)                                       \
          gl_lds16(srcB[jj] + (kofs), ldB + (buf) * BBYTES + jj * 4096); }

    GSTAGE(0, 0);
    __syncthreads();
    int cur = 0;
    const int Ab = wr * 8192 + lane * 16;
    const int Bb = wc * (NI * 2048) + lane * 16;
    for (int kt = 0; kt < KK / 64; ++kt) {
        if (kt + 1 < KK / 64) GSTAGE(cur ^ 1, (kt + 1) * 64);
        const char* ba = As + cur * ABYTES + Ab;
        const char* bb = Bs + cur * BBYTES + Bb;
#pragma unroll
        for (int ks = 0; ks < 2; ++ks) {
            bf16x8 af[4], bfr[NI];
#pragma unroll
            for (int i = 0; i < 4; ++i)
                af[i] = *(const bf16x8*)(ba + i * 2048 + ks * 1024);
#pragma unroll
            for (int ni = 0; ni < NI; ++ni)
                bfr[ni] = *(const bf16x8*)(bb + ni * 2048 + ks * 1024);
#pragma unroll
            for (int mi = 0; mi < 4; ++mi)
#pragma unroll
                for (int ni = 0; ni < NI; ++ni)
                    acc[mi][ni] = mfma16(af[mi], bfr[ni], acc[mi][ni]);
        }
        __syncthreads();
        cur ^= 1;
    }
#undef GSTAGE
}

// ---- QKV: z=0 -> Q (scaled by 0.125*log2e, head-major), z=1 -> K (head-major), z=2 -> V^T plain ----
__global__ __launch_bounds__(256, 2)
void qkv_gemm(const short* __restrict__ Xb, const short* __restrict__ Wb,
              const float* __restrict__ bq, const float* __restrict__ bk,
              const float* __restrict__ bv,
              short* __restrict__ Qo, short* __restrict__ Ko, short* __restrict__ Vto) {
    __shared__ __align__(16) char As[2 * 16384];
    __shared__ __align__(16) char Bs[2 * 16384];
    const int z = blockIdx.z;
    const short* A = Xb + (size_t)z * MM * KK;
    const short* W = Wb + (size_t)z * KK * KK;
    const float* bias = (z == 0) ? bq : (z == 1) ? bk : bv;
    const float scale = (z == 0) ? 0.125f * 1.44269504088896f : 1.0f;
    const int m0 = blockIdx.x * 128, n0 = blockIdx.y * 128;

    f32x4 zero = {0.f, 0.f, 0.f, 0.f};
    f32x4 acc[4][4];
#pragma unroll
    for (int i = 0; i < 4; ++i)
#pragma unroll
        for (int j = 0; j < 4; ++j) acc[i][j] = zero;

    gemm_core<4>(A, W, m0, n0, As, Bs, acc);

    const int tid = threadIdx.x;
    const int lane = tid & 63, w = tid >> 6;
    const int wr = w >> 1, wc = w & 1;
    const int lr = lane & 15, lg = lane >> 4;

#pragma unroll
    for (int mi = 0; mi < 4; ++mi) {
        const int mbase = m0 + wr * 64 + mi * 16 + lg * 4;
        const int b = mbase >> 11, s = mbase & 2047;
#pragma unroll
        for (int ni = 0; ni < 4; ++ni) {
            const int n = n0 + wc * 64 + ni * 16 + lr;
            const float bvv = bias[n];
            const int h = n >> 6, dk = n & 63;
            if (z == 2) {
                short4_t pk;
#pragma unroll
                for (int r = 0; r < 4; ++r) pk[r] = f2bf(acc[mi][ni][r] + bvv);
                *(short4_t*)(Vto + ((size_t)((b * HH + h) * 64 + dk) << 11) + s) = pk;
            } else {
                short* dst = (z == 0) ? Qo : Ko;
#pragma unroll
                for (int r = 0; r < 4; ++r)
                    dst[((size_t)((b * HH + h) * SS + (s + r)) << 6) + dk] =
                        f2bf((acc[mi][ni][r] + bvv) * scale);
            }
        }
    }
}

// ---- output projection: out = ctx * Wo^T + bo (fp32), 128x64 tiles ----
__global__ __launch_bounds__(256, 2)
void out_gemm(const short* __restrict__ ctx, const short* __restrict__ Wo,
              const float* __restrict__ bo, float* __restrict__ out) {
    __shared__ __align__(16) char As[2 * 16384];
    __shared__ __align__(16) char Bs[2 * 8192];
    const int m0 = blockIdx.x * 128, n0 = blockIdx.y * 64;

    f32x4 zero = {0.f, 0.f, 0.f, 0.f};
    f32x4 acc[4][2];
#pragma unroll
    for (int i = 0; i < 4; ++i)
#pragma unroll
        for (int j = 0; j < 2; ++j) acc[i][j] = zero;

    gemm_core<2>(ctx, Wo, m0, n0, As, Bs, acc);

    const int tid = threadIdx.x;
    const int lane = tid & 63, w = tid >> 6;
    const int wr = w >> 1, wc = w & 1;
    const int lr = lane & 15, lg = lane >> 4;

#pragma unroll
    for (int mi = 0; mi < 4; ++mi)
#pragma unroll
        for (int ni = 0; ni < 2; ++ni) {
            const int n = n0 + wc * 32 + ni * 16 + lr;
            const float bvv = bo[n];
#pragma unroll
            for (int r = 0; r < 4; ++r) {
                const int m = m0 + wr * 64 + mi * 16 + lg * 4 + r;
                out[(size_t)m * KK + n] = acc[mi][ni][r] + bvv;
            }
        }
}

// ---- flash attention, KV-split x2, 32x32 MFMA, swapped QK^T, fragment-order LDS ----
// Partials: Po[half][bh][s][d] bf16 (unnormalized), Pm/Pl[half][bh][s] fp32
__global__ __launch_bounds__(256, 4)
void attn_kernel(const short* __restrict__ Qg, const short* __restrict__ Kg,
                 const short* __restrict__ Vtg, const int* __restrict__ mask,
                 short* __restrict__ Po, float* __restrict__ Pm, float* __restrict__ Pl) {
    __shared__ __align__(16) short Ks[2][4096];
    __shared__ __align__(16) short Vs[2][4096];

    const int tid = threadIdx.x, w = tid >> 6, lane = tid & 63;
    const int l31 = lane & 31, hi = lane >> 5;
    const int bh = blockIdx.y, b = bh >> 4;
    const int half = blockIdx.z;
    const int q0w = blockIdx.x * 128 + w * 32;

    const short* Qh = Qg + (size_t)bh * SS * 64;
    const short* Kh = Kg + (size_t)bh * SS * 64;
    const short* Vh = Vtg + (size_t)bh * 64 * SS;
    const int* mrow = mask + b * SS;

    bf16x8 qf[4];
#pragma unroll
    for (int t = 0; t < 4; ++t)
        qf[t] = *(const bf16x8*)(Qh + (q0w + l31) * 64 + t * 16 + hi * 8);

    f32x16 octx0, octx1;
#pragma unroll
    for (int r = 0; r < 16; ++r) { octx0[r] = 0.f; octx1[r] = 0.f; }
    float mrun = -1e30f, lrun = 0.f;

    const int tq = (tid >> 6) & 3;
    const short* gk0 = Kh + (l31) * 64 + tq * 16 + hi * 8;
    const short* gk1 = Kh + (32 + l31) * 64 + tq * 16 + hi * 8;
    const short* gv0 = Vh + (size_t)(l31) * SS + tq * 16 + hi * 8;
    const short* gv1 = Vh + (size_t)(32 + l31) * SS + tq * 16 + hi * 8;
    char* lK = (char*)Ks + tid * 16;
    char* lV = (char*)Vs + tid * 16;

#define ASTAGE(buf, key0)                                      \
    { gl_lds16(gk0 + (key0) * 64, lK + (buf) * 8192);          \
      gl_lds16(gk1 + (key0) * 64, lK + 4096 + (buf) * 8192);   \
      gl_lds16(gv0 + (key0), lV + (buf) * 8192);               \
      gl_lds16(gv1 + (key0), lV + 4096 + (buf) * 8192); }

    const int it0 = half * (SS / 128), it1 = it0 + (SS / 128);
    ASTAGE(0, it0 * 64);
    __syncthreads();
    int cur = 0;

    for (int it = it0; it < it1; ++it) {
        const int key0 = it * 64;
        if (it + 1 < it1) ASTAGE(cur ^ 1, key0 + 64);

        const char* cK = (const char*)Ks + cur * 8192;
        const char* cV = (const char*)Vs + cur * 8192;

        f32x16 s0, s1;
#pragma unroll
        for (int r = 0; r < 16; ++r) { s0[r] = 0.f; s1[r] = 0.f; }
#pragma unroll
        for (int t = 0; t < 4; ++t) {
            bf16x8 a0 = *(const bf16x8*)(cK + ((0 * 4 + t) * 64 + lane) * 16);
            bf16x8 a1 = *(const bf16x8*)(cK + ((1 * 4 + t) * 64 + lane) * 16);
            s0 = mfma32(a0, qf[t], s0);
            s1 = mfma32(a1, qf[t], s1);
        }

        const int mk = mrow[key0 + lane];
        if (!__all(mk != 0)) {
#pragma unroll
            for (int r = 0; r < 16; ++r) {
                const int kl = (r & 3) + 8 * (r >> 2) + 4 * hi;
                if (mrow[key0 + kl] == 0) s0[r] = -1e9f;
                if (mrow[key0 + 32 + kl] == 0) s1[r] = -1e9f;
            }
        }

        float tv[16];
#pragma unroll
        for (int r = 0; r < 16; ++r) tv[r] = fmaxf(s0[r], s1[r]);
#pragma unroll
        for (int off = 8; off >= 1; off >>= 1)
#pragma unroll
            for (int r = 0; r < 8; ++r)
                if (r < off) tv[r] = fmaxf(tv[r], tv[r + off]);
        float tm = tv[0];
        tm = fmaxf(tm, __shfl_xor(tm, 32));

        if (!__all(tm <= mrun + 8.0f)) {
            const float mnew = fmaxf(mrun, tm);
            const float alpha = exp2a(mrun - mnew);
            lrun *= alpha;
#pragma unroll
            for (int r = 0; r < 16; ++r) {
                const int ql = (r & 3) + 8 * (r >> 2) + 4 * hi;
                const float aq = __shfl(alpha, ql);
                octx0[r] *= aq;
                octx1[r] *= aq;
            }
            mrun = mnew;
        }

#pragma unroll
        for (int r = 0; r < 16; ++r) {
            s0[r] = exp2a(s0[r] - mrun);
            s1[r] = exp2a(s1[r] - mrun);
        }
        float sv[16];
#pragma unroll
        for (int r = 0; r < 16; ++r) sv[r] = s0[r] + s1[r];
#pragma unroll
        for (int off = 8; off >= 1; off >>= 1)
#pragma unroll
            for (int r = 0; r < 8; ++r)
                if (r < off) sv[r] += sv[r + off];
        float rs = sv[0];
        rs += __shfl_xor(rs, 32);
        lrun += rs;

        bf16x8 pa[4];
#pragma unroll
        for (int kb = 0; kb < 2; ++kb) {
            const f32x16& sv16 = kb ? s1 : s0;
#pragma unroll
            for (int halfp = 0; halfp < 2; ++halfp) {
                const int base = halfp * 8;
                int A  = cvtpk(sv16[base + 0], sv16[base + 1]);
                int Bw = cvtpk(sv16[base + 2], sv16[base + 3]);
                int Cw = cvtpk(sv16[base + 4], sv16[base + 5]);
                int Dw = cvtpk(sv16[base + 6], sv16[base + 7]);
                pswap(A, Cw);
                pswap(Bw, Dw);
                union { int wv[4]; bf16x8 v; } u;
                u.wv[0] = A; u.wv[1] = Bw; u.wv[2] = Cw; u.wv[3] = Dw;
                pa[kb * 2 + halfp] = u.v;
            }
        }

#pragma unroll
        for (int kk = 0; kk < 4; ++kk) {
            bf16x8 v0 = *(const bf16x8*)(cV + ((0 * 4 + kk) * 64 + lane) * 16);
            bf16x8 v1 = *(const bf16x8*)(cV + ((1 * 4 + kk) * 64 + lane) * 16);
            octx0 = mfma32(pa[kk], v0, octx0);
            octx1 = mfma32(pa[kk], v1, octx1);
        }

        __syncthreads();
        cur ^= 1;
    }
#undef ASTAGE

    const size_t pbase = (size_t)(half * 32 + bh) * SS;
#pragma unroll
    for (int r = 0; r < 16; ++r) {
        const int ql = (r & 3) + 8 * (r >> 2) + 4 * hi;
        short* prow = Po + (pbase + q0w + ql) * 64 + l31;
        prow[0]  = f2bf(octx0[r]);
        prow[32] = f2bf(octx1[r]);
    }
    if (hi == 0) {
        Pm[pbase + q0w + l31] = mrun;
        Pl[pbase + q0w + l31] = lrun;
    }
}

// ---- combine the two KV-halves -> ctx bf16 [B][S][D] ----
__global__ __launch_bounds__(256)
void attn_combine(const short* __restrict__ Po, const float* __restrict__ Pm,
                  const float* __restrict__ Pl, short* __restrict__ ctxb) {
    const int idx = blockIdx.x * 256 + threadIdx.x;  // 0..524287
    const int d0 = (idx & 7) * 8;
    const int s  = (idx >> 3) & (SS - 1);
    const int bh = idx >> 14;
    const int b = bh >> 4, h = bh & 15;

    const size_t i1 = (size_t)bh * SS + s;
    const size_t i2 = (size_t)(32 + bh) * SS + s;
    const float m1 = Pm[i1], m2 = Pm[i2];
    const float l1 = Pl[i1], l2 = Pl[i2];
    const float m = fmaxf(m1, m2);
    const float w1 = exp2a(m1 - m), w2 = exp2a(m2 - m);
    const float inv = 1.f / (l1 * w1 + l2 * w2);

    bf16x8 o1 = *(const bf16x8*)(Po + i1 * 64 + d0);
    bf16x8 o2 = *(const bf16x8*)(Po + i2 * 64 + d0);
    bf16x8 o;
#pragma unroll
    for (int j = 0; j < 8; ++j)
        o[j] = f2bf((bf2f(o1[j]) * w1 + bf2f(o2[j]) * w2) * inv);
    *(bf16x8*)(ctxb + ((size_t)(b * SS + s)) * DD + h * 64 + d0) = o;
}

extern "C" void kernel_launch(void* const* d_in, const int* in_sizes, int n_in,
                              void* d_out, int out_size, void* d_ws, size_t ws_size,
                              hipStream_t stream) {
    const float* preQ = (const float*)d_in[0];
    const float* preK = (const float*)d_in[1];
    const float* preV = (const float*)d_in[2];
    const float* Wq   = (const float*)d_in[3];
    const float* bq   = (const float*)d_in[4];
    const float* Wk   = (const float*)d_in[5];
    const float* bk   = (const float*)d_in[6];
    const float* Wv   = (const float*)d_in[7];
    const float* bv   = (const float*)d_in[8];
    const float* Wo   = (const float*)d_in[9];
    const float* bo   = (const float*)d_in[10];
    const int*   mask = (const int*)d_in[11];
    float* out = (float*)d_out;

    char* ws = (char*)d_ws;
    short* Xb  = (short*)(ws);                           // 24 MB
    short* Wb  = (short*)(ws + (size_t)25165824);        // 8 MB
    short* Qw  = (short*)(ws + (size_t)33554432);        // 8 MB
    short* Kw  = (short*)(ws + (size_t)41943040);        // 8 MB
    short* Vtw = (short*)(ws + (size_t)50331648);        // 8 MB
    short* Ctx = (short*)(ws + (size_t)58720256);        // 8 MB
    short* Po  = (short*)(ws + (size_t)67108864);        // 16 MB
    float* Pm  = (float*)(ws + (size_t)83886080);        // 512 KB
    float* Pl  = (float*)(ws + (size_t)84410368);        // 512 KB

    conv_all<<<dim3(8192), 256, 0, stream>>>(preQ, preK, preV, Wq, Wk, Wv, Wo, Xb, Wb);
    qkv_gemm<<<dim3(32, 8, 3), 256, 0, stream>>>(Xb, Wb, bq, bk, bv, Qw, Kw, Vtw);
    attn_kernel<<<dim3(16, 32, 2), 256, 0, stream>>>(Qw, Kw, Vtw, mask, Po, Pm, Pl);
    attn_combine<<<dim3(2048), 256, 0, stream>>>(Po, Pm, Pl, Ctx);
    out_gemm<<<dim3(32, 16), 256, 0, stream>>>(Ctx, Wb + (size_t)3 * KK * KK, bo, out);
}

// Round 7
// 236.062 us; speedup vs baseline: 1.1465x; 1.1465x over previous
//
#include <hip/hip_runtime.h>

#define SS 2048
#define DD 1024
#define HH 16
#define MM 4096
#define KK 1024

typedef __attribute__((ext_vector_type(8))) short bf16x8;
typedef __attribute__((ext_vector_type(4))) float f32x4;
typedef __attribute__((ext_vector_type(16))) float f32x16;
typedef __attribute__((ext_vector_type(4))) float float4_t;
typedef __attribute__((ext_vector_type(4))) short short4_t;

__device__ __forceinline__ short f2bf(float f) {
    union { float f; unsigned u; } x; x.f = f;
    unsigned r = x.u + 0x7fffu + ((x.u >> 16) & 1u);
    return (short)(r >> 16);
}
__device__ __forceinline__ float bf2f(short s) {
    union { unsigned u; float f; } x; x.u = ((unsigned)(unsigned short)s) << 16;
    return x.f;
}

__device__ __forceinline__ f32x4 mfma16(bf16x8 a, bf16x8 b, f32x4 c) {
    return __builtin_amdgcn_mfma_f32_16x16x32_bf16(a, b, c, 0, 0, 0);
}
__device__ __forceinline__ f32x16 mfma32(bf16x8 a, bf16x8 b, f32x16 c) {
    return __builtin_amdgcn_mfma_f32_32x32x16_bf16(a, b, c, 0, 0, 0);
}

__device__ __forceinline__ void gl_lds16(const void* g, void* l) {
    __builtin_amdgcn_global_load_lds(
        (const __attribute__((address_space(1))) void*)g,
        (__attribute__((address_space(3))) void*)l, 16, 0, 0);
}

__device__ __forceinline__ float exp2a(float x) {
    float r; asm("v_exp_f32 %0, %1" : "=v"(r) : "v"(x)); return r;
}
__device__ __forceinline__ int cvtpk(float lo, float hi) {
    int r; asm("v_cvt_pk_bf16_f32 %0, %1, %2" : "=v"(r) : "v"(lo), "v"(hi)); return r;
}
__device__ __forceinline__ void pswap(int& a, int& b) {
    asm("v_permlane32_swap_b32 %0, %1" : "+v"(a), "+v"(b));
}

// ---------------- fused conversion pass: fp32 -> bf16 (X planes + W planes) ----------------
__global__ __launch_bounds__(256)
void conv_all(const float* __restrict__ x0, const float* __restrict__ x1,
              const float* __restrict__ x2,
              const float* __restrict__ w0, const float* __restrict__ w1,
              const float* __restrict__ w2, const float* __restrict__ w3,
              short* __restrict__ Xb, short* __restrict__ Wb) {
    const int bid = blockIdx.x;
    const float* src;
    short* dst;
    size_t i;
    if (bid < 6144) {
        const int plane = bid >> 11, idx = bid & 2047;
        src = (plane == 0) ? x0 : (plane == 1) ? x1 : x2;
        i = ((size_t)idx * 256 + threadIdx.x) * 8;
        dst = Xb + (size_t)plane * MM * KK;
    } else {
        const int b2 = bid - 6144;
        const int plane = b2 >> 9, idx = b2 & 511;
        src = (plane == 0) ? w0 : (plane == 1) ? w1 : (plane == 2) ? w2 : w3;
        i = ((size_t)idx * 256 + threadIdx.x) * 8;
        dst = Wb + (size_t)plane * KK * KK;
    }
    float4_t a = *(const float4_t*)(src + i);
    float4_t b = *(const float4_t*)(src + i + 4);
    bf16x8 o;
#pragma unroll
    for (int e = 0; e < 4; ++e) { o[e] = f2bf(a[e]); o[4 + e] = f2bf(b[e]); }
    *(bf16x8*)(dst + i) = o;
}

// ---------------- bf16 GEMM core, BK=32, coalesced staging + in-row XOR swizzle ----------------
// A [M][K] bf16, W [N][K] bf16, C = A*W^T. Tile: 128 x (NI*32). 4 waves (2x2).
// LDS rows of 32 shorts (64B). Global src k-chunk ^= (row>>1)&3 (within-row permutation,
// coalescing preserved, LDS dest linear); reads apply the same XOR -> 2-way max conflicts.
template <int NI>
__device__ __forceinline__ void gemm_core(const short* __restrict__ A,
                                          const short* __restrict__ Bw,
                                          int m0, int n0,
                                          char* As, char* Bs,
                                          f32x4 acc[4][NI]) {
    const int tid = threadIdx.x;
    const int lane = tid & 63, w = tid >> 6;
    const int wr = w >> 1, wc = w & 1;
    const int lr = lane & 15, lg = lane >> 4;

    // staging: chunk c -> row=c>>2, kc=(c&3)^((row>>1)&3). Row+64 has same swizzle.
    const int rA = tid >> 2;
    const int kcA = (tid & 3) ^ ((rA >> 1) & 3);
    const short* ga0 = A + (size_t)(m0 + rA) * KK + kcA * 8;
    const short* ga1 = ga0 + (size_t)64 * KK;
    const short* gb0 = Bw + (size_t)(n0 + rA) * KK + kcA * 8;
    const short* gb1 = gb0 + (size_t)64 * KK;
    char* lA = As + tid * 16;
    char* lB = Bs + tid * 16;
    constexpr int BBUF = NI * 2048;

#define GSTAGE(buf, kofs)                                        \
    { gl_lds16(ga0 + (kofs), lA + (buf) * 8192);                 \
      gl_lds16(ga1 + (kofs), lA + 4096 + (buf) * 8192);          \
      gl_lds16(gb0 + (kofs), lB + (buf) * BBUF);                 \
      if constexpr (NI == 4)                                     \
          gl_lds16(gb1 + (kofs), lB + 4096 + (buf) * BBUF); }

    GSTAGE(0, 0);
    __syncthreads();
    int cur = 0;
    const int swz = ((lr >> 1) & 3) * 16;
    const int aoff = (wr * 64 + lr) * 64 + (lg * 16 ^ swz);
    const int boff = (wc * (NI * 16) + lr) * 64 + (lg * 16 ^ swz);
    for (int kt = 0; kt < KK / 32; ++kt) {
        if (kt + 1 < KK / 32) GSTAGE(cur ^ 1, (kt + 1) * 32);
        const char* ba = As + cur * 8192 + aoff;
        const char* bb = Bs + cur * BBUF + boff;
        bf16x8 af[4], bfr[NI];
#pragma unroll
        for (int i = 0; i < 4; ++i)
            af[i] = *(const bf16x8*)(ba + i * 1024);
#pragma unroll
        for (int ni = 0; ni < NI; ++ni)
            bfr[ni] = *(const bf16x8*)(bb + ni * 1024);
#pragma unroll
        for (int mi = 0; mi < 4; ++mi)
#pragma unroll
            for (int ni = 0; ni < NI; ++ni)
                acc[mi][ni] = mfma16(af[mi], bfr[ni], acc[mi][ni]);
        __syncthreads();
        cur ^= 1;
    }
#undef GSTAGE
}

// ---- QKV: z=0 -> Q (scaled by 0.125*log2e, head-major), z=1 -> K (head-major), z=2 -> V^T plain ----
__global__ __launch_bounds__(256, 4)
void qkv_gemm(const short* __restrict__ Xb, const short* __restrict__ Wb,
              const float* __restrict__ bq, const float* __restrict__ bk,
              const float* __restrict__ bv,
              short* __restrict__ Qo, short* __restrict__ Ko, short* __restrict__ Vto) {
    __shared__ __align__(16) char As[2 * 8192];
    __shared__ __align__(16) char Bs[2 * 8192];
    const int z = blockIdx.z;
    const short* A = Xb + (size_t)z * MM * KK;
    const short* W = Wb + (size_t)z * KK * KK;
    const float* bias = (z == 0) ? bq : (z == 1) ? bk : bv;
    const float scale = (z == 0) ? 0.125f * 1.44269504088896f : 1.0f;
    const int m0 = blockIdx.x * 128, n0 = blockIdx.y * 128;

    f32x4 zero = {0.f, 0.f, 0.f, 0.f};
    f32x4 acc[4][4];
#pragma unroll
    for (int i = 0; i < 4; ++i)
#pragma unroll
        for (int j = 0; j < 4; ++j) acc[i][j] = zero;

    gemm_core<4>(A, W, m0, n0, As, Bs, acc);

    const int tid = threadIdx.x;
    const int lane = tid & 63, w = tid >> 6;
    const int wr = w >> 1, wc = w & 1;
    const int lr = lane & 15, lg = lane >> 4;

#pragma unroll
    for (int mi = 0; mi < 4; ++mi) {
        const int mbase = m0 + wr * 64 + mi * 16 + lg * 4;
        const int b = mbase >> 11, s = mbase & 2047;
#pragma unroll
        for (int ni = 0; ni < 4; ++ni) {
            const int n = n0 + wc * 64 + ni * 16 + lr;
            const float bvv = bias[n];
            const int h = n >> 6, dk = n & 63;
            if (z == 2) {
                short4_t pk;
#pragma unroll
                for (int r = 0; r < 4; ++r) pk[r] = f2bf(acc[mi][ni][r] + bvv);
                *(short4_t*)(Vto + ((size_t)((b * HH + h) * 64 + dk) << 11) + s) = pk;
            } else {
                short* dst = (z == 0) ? Qo : Ko;
#pragma unroll
                for (int r = 0; r < 4; ++r)
                    dst[((size_t)((b * HH + h) * SS + (s + r)) << 6) + dk] =
                        f2bf((acc[mi][ni][r] + bvv) * scale);
            }
        }
    }
}

// ---- output projection: out = ctx * Wo^T + bo (fp32), 128x64 tiles ----
__global__ __launch_bounds__(256, 4)
void out_gemm(const short* __restrict__ ctx, const short* __restrict__ Wo,
              const float* __restrict__ bo, float* __restrict__ out) {
    __shared__ __align__(16) char As[2 * 8192];
    __shared__ __align__(16) char Bs[2 * 4096];
    const int m0 = blockIdx.x * 128, n0 = blockIdx.y * 64;

    f32x4 zero = {0.f, 0.f, 0.f, 0.f};
    f32x4 acc[4][2];
#pragma unroll
    for (int i = 0; i < 4; ++i)
#pragma unroll
        for (int j = 0; j < 2; ++j) acc[i][j] = zero;

    gemm_core<2>(ctx, Wo, m0, n0, As, Bs, acc);

    const int tid = threadIdx.x;
    const int lane = tid & 63, w = tid >> 6;
    const int wr = w >> 1, wc = w & 1;
    const int lr = lane & 15, lg = lane >> 4;

#pragma unroll
    for (int mi = 0; mi < 4; ++mi)
#pragma unroll
        for (int ni = 0; ni < 2; ++ni) {
            const int n = n0 + wc * 32 + ni * 16 + lr;
            const float bvv = bo[n];
#pragma unroll
            for (int r = 0; r < 4; ++r) {
                const int m = m0 + wr * 64 + mi * 16 + lg * 4 + r;
                out[(size_t)m * KK + n] = acc[mi][ni][r] + bvv;
            }
        }
}

// ---- flash attention, KV-split x2, 32x32 MFMA, swapped QK^T, fragment-order LDS ----
// Partials: Po[half][bh][s][d] bf16 (unnormalized), Pm/Pl[half][bh][s] fp32
__global__ __launch_bounds__(256, 4)
void attn_kernel(const short* __restrict__ Qg, const short* __restrict__ Kg,
                 const short* __restrict__ Vtg, const int* __restrict__ mask,
                 short* __restrict__ Po, float* __restrict__ Pm, float* __restrict__ Pl) {
    __shared__ __align__(16) short Ks[2][4096];
    __shared__ __align__(16) short Vs[2][4096];

    const int tid = threadIdx.x, w = tid >> 6, lane = tid & 63;
    const int l31 = lane & 31, hi = lane >> 5;
    const int bh = blockIdx.y, b = bh >> 4;
    const int half = blockIdx.z;
    const int q0w = blockIdx.x * 128 + w * 32;

    const short* Qh = Qg + (size_t)bh * SS * 64;
    const short* Kh = Kg + (size_t)bh * SS * 64;
    const short* Vh = Vtg + (size_t)bh * 64 * SS;
    const int* mrow = mask + b * SS;

    bf16x8 qf[4];
#pragma unroll
    for (int t = 0; t < 4; ++t)
        qf[t] = *(const bf16x8*)(Qh + (q0w + l31) * 64 + t * 16 + hi * 8);

    f32x16 octx0, octx1;
#pragma unroll
    for (int r = 0; r < 16; ++r) { octx0[r] = 0.f; octx1[r] = 0.f; }
    float mrun = -1e30f, lrun = 0.f;

    const int tq = (tid >> 6) & 3;
    const short* gk0 = Kh + (l31) * 64 + tq * 16 + hi * 8;
    const short* gk1 = Kh + (32 + l31) * 64 + tq * 16 + hi * 8;
    const short* gv0 = Vh + (size_t)(l31) * SS + tq * 16 + hi * 8;
    const short* gv1 = Vh + (size_t)(32 + l31) * SS + tq * 16 + hi * 8;
    char* lK = (char*)Ks + tid * 16;
    char* lV = (char*)Vs + tid * 16;

#define ASTAGE(buf, key0)                                      \
    { gl_lds16(gk0 + (key0) * 64, lK + (buf) * 8192);          \
      gl_lds16(gk1 + (key0) * 64, lK + 4096 + (buf) * 8192);   \
      gl_lds16(gv0 + (key0), lV + (buf) * 8192);               \
      gl_lds16(gv1 + (key0), lV + 4096 + (buf) * 8192); }

    const int it0 = half * (SS / 128), it1 = it0 + (SS / 128);
    ASTAGE(0, it0 * 64);
    __syncthreads();
    int cur = 0;

    for (int it = it0; it < it1; ++it) {
        const int key0 = it * 64;
        if (it + 1 < it1) ASTAGE(cur ^ 1, key0 + 64);

        const char* cK = (const char*)Ks + cur * 8192;
        const char* cV = (const char*)Vs + cur * 8192;

        f32x16 s0, s1;
#pragma unroll
        for (int r = 0; r < 16; ++r) { s0[r] = 0.f; s1[r] = 0.f; }
#pragma unroll
        for (int t = 0; t < 4; ++t) {
            bf16x8 a0 = *(const bf16x8*)(cK + ((0 * 4 + t) * 64 + lane) * 16);
            bf16x8 a1 = *(const bf16x8*)(cK + ((1 * 4 + t) * 64 + lane) * 16);
            s0 = mfma32(a0, qf[t], s0);
            s1 = mfma32(a1, qf[t], s1);
        }

        const int mk = mrow[key0 + lane];
        if (!__all(mk != 0)) {
#pragma unroll
            for (int r = 0; r < 16; ++r) {
                const int kl = (r & 3) + 8 * (r >> 2) + 4 * hi;
                if (mrow[key0 + kl] == 0) s0[r] = -1e9f;
                if (mrow[key0 + 32 + kl] == 0) s1[r] = -1e9f;
            }
        }

        float tv[16];
#pragma unroll
        for (int r = 0; r < 16; ++r) tv[r] = fmaxf(s0[r], s1[r]);
#pragma unroll
        for (int off = 8; off >= 1; off >>= 1)
#pragma unroll
            for (int r = 0; r < 8; ++r)
                if (r < off) tv[r] = fmaxf(tv[r], tv[r + off]);
        float tm = tv[0];
        tm = fmaxf(tm, __shfl_xor(tm, 32));

        if (!__all(tm <= mrun + 8.0f)) {
            const float mnew = fmaxf(mrun, tm);
            const float alpha = exp2a(mrun - mnew);
            lrun *= alpha;
#pragma unroll
            for (int r = 0; r < 16; ++r) {
                const int ql = (r & 3) + 8 * (r >> 2) + 4 * hi;
                const float aq = __shfl(alpha, ql);
                octx0[r] *= aq;
                octx1[r] *= aq;
            }
            mrun = mnew;
        }

#pragma unroll
        for (int r = 0; r < 16; ++r) {
            s0[r] = exp2a(s0[r] - mrun);
            s1[r] = exp2a(s1[r] - mrun);
        }
        float sv[16];
#pragma unroll
        for (int r = 0; r < 16; ++r) sv[r] = s0[r] + s1[r];
#pragma unroll
        for (int off = 8; off >= 1; off >>= 1)
#pragma unroll
            for (int r = 0; r < 8; ++r)
                if (r < off) sv[r] += sv[r + off];
        float rs = sv[0];
        rs += __shfl_xor(rs, 32);
        lrun += rs;

        bf16x8 pa[4];
#pragma unroll
        for (int kb = 0; kb < 2; ++kb) {
            const f32x16& sv16 = kb ? s1 : s0;
#pragma unroll
            for (int halfp = 0; halfp < 2; ++halfp) {
                const int base = halfp * 8;
                int A  = cvtpk(sv16[base + 0], sv16[base + 1]);
                int Bw = cvtpk(sv16[base + 2], sv16[base + 3]);
                int Cw = cvtpk(sv16[base + 4], sv16[base + 5]);
                int Dw = cvtpk(sv16[base + 6], sv16[base + 7]);
                pswap(A, Cw);
                pswap(Bw, Dw);
                union { int wv[4]; bf16x8 v; } u;
                u.wv[0] = A; u.wv[1] = Bw; u.wv[2] = Cw; u.wv[3] = Dw;
                pa[kb * 2 + halfp] = u.v;
            }
        }

#pragma unroll
        for (int kk = 0; kk < 4; ++kk) {
            bf16x8 v0 = *(const bf16x8*)(cV + ((0 * 4 + kk) * 64 + lane) * 16);
            bf16x8 v1 = *(const bf16x8*)(cV + ((1 * 4 + kk) * 64 + lane) * 16);
            octx0 = mfma32(pa[kk], v0, octx0);
            octx1 = mfma32(pa[kk], v1, octx1);
        }

        __syncthreads();
        cur ^= 1;
    }
#undef ASTAGE

    const size_t pbase = (size_t)(half * 32 + bh) * SS;
#pragma unroll
    for (int r = 0; r < 16; ++r) {
        const int ql = (r & 3) + 8 * (r >> 2) + 4 * hi;
        short* prow = Po + (pbase + q0w + ql) * 64 + l31;
        prow[0]  = f2bf(octx0[r]);
        prow[32] = f2bf(octx1[r]);
    }
    if (hi == 0) {
        Pm[pbase + q0w + l31] = mrun;
        Pl[pbase + q0w + l31] = lrun;
    }
}

// ---- combine the two KV-halves -> ctx bf16 [B][S][D] ----
__global__ __launch_bounds__(256)
void attn_combine(const short* __restrict__ Po, const float* __restrict__ Pm,
                  const float* __restrict__ Pl, short* __restrict__ ctxb) {
    const int idx = blockIdx.x * 256 + threadIdx.x;  // 0..524287
    const int d0 = (idx & 7) * 8;
    const int s  = (idx >> 3) & (SS - 1);
    const int bh = idx >> 14;
    const int b = bh >> 4, h = bh & 15;

    const size_t i1 = (size_t)bh * SS + s;
    const size_t i2 = (size_t)(32 + bh) * SS + s;
    const float m1 = Pm[i1], m2 = Pm[i2];
    const float l1 = Pl[i1], l2 = Pl[i2];
    const float m = fmaxf(m1, m2);
    const float w1 = exp2a(m1 - m), w2 = exp2a(m2 - m);
    const float inv = 1.f / (l1 * w1 + l2 * w2);

    bf16x8 o1 = *(const bf16x8*)(Po + i1 * 64 + d0);
    bf16x8 o2 = *(const bf16x8*)(Po + i2 * 64 + d0);
    bf16x8 o;
#pragma unroll
    for (int j = 0; j < 8; ++j)
        o[j] = f2bf((bf2f(o1[j]) * w1 + bf2f(o2[j]) * w2) * inv);
    *(bf16x8*)(ctxb + ((size_t)(b * SS + s)) * DD + h * 64 + d0) = o;
}

extern "C" void kernel_launch(void* const* d_in, const int* in_sizes, int n_in,
                              void* d_out, int out_size, void* d_ws, size_t ws_size,
                              hipStream_t stream) {
    const float* preQ = (const float*)d_in[0];
    const float* preK = (const float*)d_in[1];
    const float* preV = (const float*)d_in[2];
    const float* Wq   = (const float*)d_in[3];
    const float* bq   = (const float*)d_in[4];
    const float* Wk   = (const float*)d_in[5];
    const float* bk   = (const float*)d_in[6];
    const float* Wv   = (const float*)d_in[7];
    const float* bv   = (const float*)d_in[8];
    const float* Wo   = (const float*)d_in[9];
    const float* bo   = (const float*)d_in[10];
    const int*   mask = (const int*)d_in[11];
    float* out = (float*)d_out;

    char* ws = (char*)d_ws;
    short* Xb  = (short*)(ws);                           // 24 MB
    short* Wb  = (short*)(ws + (size_t)25165824);        // 8 MB
    short* Qw  = (short*)(ws + (size_t)33554432);        // 8 MB
    short* Kw  = (short*)(ws + (size_t)41943040);        // 8 MB
    short* Vtw = (short*)(ws + (size_t)50331648);        // 8 MB
    short* Ctx = (short*)(ws + (size_t)58720256);        // 8 MB
    short* Po  = (short*)(ws + (size_t)67108864);        // 16 MB
    float* Pm  = (float*)(ws + (size_t)83886080);        // 512 KB
    float* Pl  = (float*)(ws + (size_t)84410368);        // 512 KB

    conv_all<<<dim3(8192), 256, 0, stream>>>(preQ, preK, preV, Wq, Wk, Wv, Wo, Xb, Wb);
    qkv_gemm<<<dim3(32, 8, 3), 256, 0, stream>>>(Xb, Wb, bq, bk, bv, Qw, Kw, Vtw);
    attn_kernel<<<dim3(16, 32, 2), 256, 0, stream>>>(Qw, Kw, Vtw, mask, Po, Pm, Pl);
    attn_combine<<<dim3(2048), 256, 0, stream>>>(Po, Pm, Pl, Ctx);
    out_gemm<<<dim3(32, 16), 256, 0, stream>>>(Ctx, Wb + (size_t)3 * KK * KK, bo, out);
}